// Round 10
// baseline (3775.763 us; speedup 1.0000x reference)
//
#include <hip/hip_runtime.h>
#include <math.h>

typedef __attribute__((ext_vector_type(8))) short short8;
typedef __attribute__((ext_vector_type(4))) float floatx4;
typedef unsigned short ushort_t;
typedef unsigned int uint_t;
typedef unsigned long long ull_t;

// Problem constants
constexpr int C_B   = 512;
constexpr int C_T   = 365;
constexpr int C_IN  = 10;
constexpr int C_H   = 256;
constexpr int C_OUT = 20;

// 16 strips x 12 blocks (4 L0 + 8 L1), 32 rows/strip — round-7 compute shape
// (best measured). Round 10: NO flag protocol. Every h element is an 8-byte
// (value32 | tag32) word; consumers poll their own data words (tag==step).
// One fabric trip per chain hop; no publish; LDS-only barriers (no store drain).
constexpr int NB  = 192;

// Weight planes (ushort units): mat(3) x plane(hi,lo) x [48nt][8ks][64][8]
constexpr size_t PLANE_U = 48ull * 8 * 64 * 8;   // 196608 ushorts
constexpr size_t US_H    = 6 * PLANE_U;          // ushort offset of tagged-h region
// Tagged h planes (ull each): h0 -> planes 0,1,2 (ring k%3); h1 -> 3,4 (ring).
constexpr size_t HP_E    = 512ull * 256;         // ull per plane
// sync (uint) after 5 planes: cons0[mt] @ +mt*32 (L1 consumed-counter, lazy WAR)
constexpr int SY_TOT = 1024;
constexpr unsigned SPIN_MAIN = 4096;             // valve: visible, never hangs

__device__ __forceinline__ float fsig(float v)  { return 1.0f / (1.0f + __expf(-v)); }
__device__ __forceinline__ float ftanh(float v) { return 2.0f / (1.0f + __expf(-2.0f * v)) - 1.0f; }

__device__ __forceinline__ void split1(float x, ushort_t& hi, ushort_t& lo) {
    unsigned u = __float_as_uint(x);
    hi = (ushort_t)(u >> 16);
    float r = x - __uint_as_float(u & 0xffff0000u);
    lo = (ushort_t)(__float_as_uint(r) >> 16);
}
__device__ __forceinline__ uint_t packsplit(float x) {
    unsigned u = __float_as_uint(x);
    unsigned hib = u & 0xffff0000u;
    float r = x - __uint_as_float(hib);
    return hib | (__float_as_uint(r) >> 16);
}
__device__ __forceinline__ float lds_h(const ushort_t* hi, const ushort_t* lo, int idx) {
    return __uint_as_float(((unsigned)hi[idx]) << 16) + __uint_as_float(((unsigned)lo[idx]) << 16);
}

// AGENT-scope primitives (proven mechanism across rounds 1-9)
__device__ __forceinline__ ull_t ald8(const ull_t* p) {
    return __hip_atomic_load(p, __ATOMIC_RELAXED, __HIP_MEMORY_SCOPE_AGENT);
}
__device__ __forceinline__ void ast8(ull_t* p, ull_t v) {
    __hip_atomic_store(p, v, __ATOMIC_RELAXED, __HIP_MEMORY_SCOPE_AGENT);
}
__device__ __forceinline__ uint_t ald(const uint_t* p) {
    return __hip_atomic_load(p, __ATOMIC_RELAXED, __HIP_MEMORY_SCOPE_AGENT);
}
__device__ __forceinline__ uint_t spin_ge(uint_t* p, uint_t tgt) {
    uint_t v = ald(p), it = 0;
    while (v < tgt) {
        if (++it > SPIN_MAIN) break;   // valve
        __builtin_amdgcn_s_sleep(2);
        v = ald(p);
    }
    return v;
}

// LDS-only barrier: does NOT drain outstanding global stores (vmcnt untouched)
__device__ __forceinline__ void barrier_lds() {
    asm volatile("s_waitcnt lgkmcnt(0)\n\ts_barrier" ::: "memory");
}

__device__ __forceinline__ void commit4(uint_t u0, uint_t u1, uint_t u2, uint_t u3,
                                        ushort_t* s_hi, ushort_t* s_lo) {
    uint2 hv, lv;
    hv.x = (u0 >> 16) | (u1 & 0xffff0000u);
    hv.y = (u2 >> 16) | (u3 & 0xffff0000u);
    lv.x = (u0 & 0xffffu) | (u1 << 16);
    lv.y = (u2 & 0xffffu) | (u3 << 16);
    *(uint2*)s_hi = hv;
    *(uint2*)s_lo = lv;
}

// Poll+stage one [32][256] tagged plane tile into hi/lo LDS. Each thread owns
// 32 elements; retries only stale ones. Fully parallel — no serialized flag.
__device__ __forceinline__ void stage_tagged(const ull_t* __restrict__ src, uint_t tag,
                                             ushort_t* s_hi, ushort_t* s_lo, int tid) {
    const int c0 = (tid & 63) * 4;
    const int r0 = tid >> 6;
    const ull_t* p = src + r0 * 256 + c0;
#pragma unroll
    for (int hb = 0; hb < 2; hb++) {
        ull_t v[16];
#pragma unroll
        for (int u = 0; u < 16; u++)
            v[u] = ald8(p + (hb * 4 + (u >> 2)) * 1024 + (u & 3));
        uint_t it = 0;
        for (;;) {
            uint_t bad = 0;
#pragma unroll
            for (int u = 0; u < 16; u++)
                bad |= ((uint_t)(v[u] >> 32) != tag) ? (1u << u) : 0u;
            if (!bad || it > SPIN_MAIN) break;   // valve: wrong-but-terminating
            ++it;
            __builtin_amdgcn_s_sleep(1);
#pragma unroll
            for (int u = 0; u < 16; u++)
                if (bad & (1u << u)) v[u] = ald8(p + (hb * 4 + (u >> 2)) * 1024 + (u & 3));
        }
#pragma unroll
        for (int u = 0; u < 16; u += 4) {
            const int row = r0 + (hb * 4 + (u >> 2)) * 4;
            const int so = row * 264 + c0;
            commit4((uint_t)v[u], (uint_t)v[u + 1], (uint_t)v[u + 2], (uint_t)v[u + 3],
                    s_hi + so, s_lo + so);
        }
    }
}

// ---------------- weight pre-pack + tag-plane/counter zeroing ----------------
__global__ __launch_bounds__(256) void prep_pack(const float* __restrict__ Whh0,
                                                 const float* __restrict__ Wih1,
                                                 const float* __restrict__ Whh1,
                                                 ushort_t* __restrict__ PW) {
    const int blk = blockIdx.x;            // 144 = mat(3) x g(3) x jb(16)
    const int tid = threadIdx.x;

    // zero all 5 tagged planes (tags become 0; valid tags are >=1) + counters.
    // Runs every launch (graph replay) -> stale-tag acceptance is impossible.
    ull_t* Z = (ull_t*)(PW + US_H);
    for (size_t u = (size_t)blk * 256 + tid; u < 5 * HP_E; u += 144 * 256)
        ast8(Z + u, 0ull);
    if (blk == 0) {
        uint_t* SY = (uint_t*)(Z + 5 * HP_E);
        for (int u = tid; u < SY_TOT; u += 256)
            __hip_atomic_store(SY + u, 0u, __ATOMIC_RELAXED, __HIP_MEMORY_SCOPE_AGENT);
    }

    const int mat = blk / 48;
    const int rem = blk % 48;
    const int g   = rem / 16;
    const int jb  = rem % 16;
    const float* S = (mat == 0) ? Whh0 : (mat == 1) ? Wih1 : Whh1;

    const int jl  = tid >> 4;
    const int kc  = tid & 15;
    const int j   = jb * 16 + jl;
    const int nt  = jb * 3 + g;

    const float* src = S + (g * 256 + j) * 256 + kc * 16;
    float f[16];
#pragma unroll
    for (int q = 0; q < 4; q++) {
        float4 v = *(const float4*)(src + q * 4);
        f[q*4+0] = v.x; f[q*4+1] = v.y; f[q*4+2] = v.z; f[q*4+3] = v.w;
    }
    ushort_t hi[16], lo[16];
#pragma unroll
    for (int e = 0; e < 16; e++) split1(f[e], hi[e], lo[e]);

    ushort_t* dhi = PW + (size_t)(mat * 2 + 0) * PLANE_U;
    ushort_t* dlo = PW + (size_t)(mat * 2 + 1) * PLANE_U;
    const int ks = kc >> 1;
#pragma unroll
    for (int hh = 0; hh < 2; hh++) {
        const int quad = (kc & 1) * 2 + hh;
        const int L    = quad * 16 + jl;
        const size_t base = ((size_t)(nt * 8 + ks)) * 512 + L * 8;
        short8 vh, vl;
#pragma unroll
        for (int e = 0; e < 8; e++) { vh[e] = (short)hi[hh*8+e]; vl[e] = (short)lo[hh*8+e]; }
        *(short8*)(dhi + base) = vh;
        *(short8*)(dlo + base) = vl;
    }
}

// 3 N-tiles x full K=256, 3-pass split-bf16, two M-tiles sharing B regs (reuse=6).
__device__ __forceinline__ void wave_gemm(const ushort_t* sh_hi, const ushort_t* sh_lo,
                                          const ushort_t* __restrict__ bh_base,
                                          const ushort_t* __restrict__ bl_base,
                                          int jbg, int lane, floatx4 acc[3][2]) {
    const int m = lane & 15, quad = lane >> 4;
    const int aoff = m * 264 + quad * 8;
#pragma unroll
    for (int ks = 0; ks < 8; ks++) {
        short8 a0h = *(const short8*)(sh_hi + aoff + ks * 32);
        short8 a0l = *(const short8*)(sh_lo + aoff + ks * 32);
        short8 a1h = *(const short8*)(sh_hi + aoff + 16 * 264 + ks * 32);
        short8 a1l = *(const short8*)(sh_lo + aoff + 16 * 264 + ks * 32);
#pragma unroll
        for (int g = 0; g < 3; g++) {
            const size_t boff = (size_t)(jbg * 3 + g) * 4096 + (size_t)ks * 512 + lane * 8;
            short8 bh = *(const short8*)(bh_base + boff);
            short8 bl = *(const short8*)(bl_base + boff);
            acc[g][0] = __builtin_amdgcn_mfma_f32_16x16x32_bf16(a0h, bh, acc[g][0], 0, 0, 0);
            acc[g][0] = __builtin_amdgcn_mfma_f32_16x16x32_bf16(a0l, bh, acc[g][0], 0, 0, 0);
            acc[g][0] = __builtin_amdgcn_mfma_f32_16x16x32_bf16(a0h, bl, acc[g][0], 0, 0, 0);
            acc[g][1] = __builtin_amdgcn_mfma_f32_16x16x32_bf16(a1h, bh, acc[g][1], 0, 0, 0);
            acc[g][1] = __builtin_amdgcn_mfma_f32_16x16x32_bf16(a1l, bh, acc[g][1], 0, 0, 0);
            acc[g][1] = __builtin_amdgcn_mfma_f32_16x16x32_bf16(a1h, bl, acc[g][1], 0, 0, 0);
        }
    }
}

__global__ __launch_bounds__(256) void gru_persistent(
    const float* __restrict__ x,
    const float* __restrict__ Wih0,
    const float* __restrict__ bih0, const float* __restrict__ bhh0,
    const float* __restrict__ bih1, const float* __restrict__ bhh1,
    ushort_t* __restrict__ WS)
{
    __shared__ __align__(16) ushort_t shA_hi[32 * 264], shA_lo[32 * 264];
    __shared__ __align__(16) ushort_t shB_hi[32 * 264], shB_lo[32 * 264];
    __shared__ float xs[32][C_IN];
    __shared__ float ldH[2][3][32][17];

    const int tid  = threadIdx.x;
    const int lane = tid & 63;
    const int w    = tid >> 6;
    const int jlo  = lane & 15;
    const int quad = lane >> 4;
    const int bid  = blockIdx.x;

    const int slot = bid >> 3;                 // 0..23
    const int mt   = (bid & 7) + ((slot >= 12) ? 8 : 0);
    const int role = (slot >= 12) ? slot - 12 : slot;   // 0..11
    const bool isL0 = role < 4;
    const int ng = isL0 ? role : role - 4;
    const int b0 = mt * 32;

    ull_t* const HQ    = (ull_t*)(WS + US_H);
    uint_t* const cons0 = (uint_t*)(HQ + 5 * HP_E) + mt * 32;

    if (isL0) {
        // ================= L0: the serial chain =================
        const int jbg = ng * 4 + w;
        const int j   = jbg * 16 + jlo;
        float wxr[C_IN], wxz[C_IN], wxn[C_IN];
#pragma unroll
        for (int i = 0; i < C_IN; i++) {
            wxr[i] = Wih0[j * C_IN + i];
            wxz[i] = Wih0[(256 + j) * C_IN + i];
            wxn[i] = Wih0[(512 + j) * C_IN + i];
        }
        const float b_r  = bih0[j] + bhh0[j];
        const float b_z  = bih0[256 + j] + bhh0[256 + j];
        const float b_in = bih0[512 + j];
        const float b_hn = bhh0[512 + j];
        const int rA = tid / C_IN, cA = tid - rA * C_IN;
        const int uB = tid + 256;
        const int rB = uB / C_IN, cB = uB - rB * C_IN;
        const int xoffA = (b0 + rA) * (C_T * C_IN) + cA;
        const int xoffB = (b0 + rB) * (C_T * C_IN) + cB;
        uint_t consc = 0;

#pragma unroll 1
        for (int k = 0; k < C_T; ++k) {
            const bool l0z = (k == 0);
            float xa = x[xoffA + k * C_IN];
            float xb = 0.f;
            if (tid < 64) xb = x[xoffB + k * C_IN];

            if (!l0z)
                stage_tagged(HQ + (size_t)((k - 1) % 3) * HP_E + b0 * 256,
                             (uint_t)k, shA_hi, shA_lo, tid);
            xs[rA][cA] = xa;
            if (tid < 64) xs[rB][cB] = xb;
            barrier_lds();

            // lazy WAR check: ring-3 overwrite of h0_{k-3} needs all 8 L1
            // blocks past iter k-2 (cons0 >= 8(k-1)). Cached -> normally free.
            if (k >= 3) {
                const uint_t need = 8u * (uint_t)(k - 1);
                if (consc < need) consc = spin_ge(cons0, need);
            }

            floatx4 acc[3][2];
#pragma unroll
            for (int g = 0; g < 3; g++) { acc[g][0] = (floatx4){0,0,0,0}; acc[g][1] = (floatx4){0,0,0,0}; }
            if (!l0z)
                wave_gemm(shA_hi, shA_lo, WS, WS + PLANE_U, jbg, lane, acc);

            ull_t* const dst = HQ + (size_t)(k % 3) * HP_E;
            const ull_t tag = ((ull_t)(k + 1)) << 32;
#pragma unroll
            for (int m = 0; m < 2; m++) {
#pragma unroll
                for (int r = 0; r < 4; r++) {
                    const int row = m * 16 + quad * 4 + r;
                    float xrv = 0.f, xzv = 0.f, xnv = 0.f;
#pragma unroll
                    for (int i = 0; i < C_IN; i++) {
                        const float xvv = xs[row][i];
                        xrv += xvv * wxr[i]; xzv += xvv * wxz[i]; xnv += xvv * wxn[i];
                    }
                    const float hp = l0z ? 0.f : lds_h(shA_hi, shA_lo, row * 264 + j);
                    const float ar  = acc[0][m][r] + xrv + b_r;
                    const float az  = acc[1][m][r] + xzv + b_z;
                    const float inn = xnv + b_in;
                    const float hn  = acc[2][m][r] + b_hn;
                    const float rg = fsig(ar), zg = fsig(az);
                    const float nn = ftanh(inn + rg * hn);
                    const float hv = zg * (hp - nn) + nn;
                    ast8(dst + (b0 + row) * 256 + j, (ull_t)packsplit(hv) | tag);
                }
            }
            barrier_lds();   // LDS reuse guard only; stores drain in background
        }
    } else {
        // ================= L1 =================
        const int mat   = w >> 1;            // 0 = Wih1 x h0, 1 = Whh1 x h1
        const int jbsub = w & 1;
        const int jbg   = ng * 2 + jbsub;
        const int j     = jbg * 16 + jlo;
        float b_r = 0.f, b_z = 0.f, b_in = 0.f, b_hn = 0.f;
        if (mat == 0) {
            b_r  = bih1[j] + bhh1[j];
            b_z  = bih1[256 + j] + bhh1[256 + j];
            b_in = bih1[512 + j];
            b_hn = bhh1[512 + j];
        }

#pragma unroll 1
        for (int k = 0; k <= C_T; ++k) {
            const bool do1 = (k >= 1);
            const bool l1z = (k == 1);

            if (do1) {
                stage_tagged(HQ + (size_t)((k - 1) % 3) * HP_E + b0 * 256,
                             (uint_t)k, shA_hi, shA_lo, tid);
                if (!l1z)
                    stage_tagged(HQ + (size_t)(3 + (k & 1)) * HP_E + b0 * 256,
                                 (uint_t)(k - 1), shB_hi, shB_lo, tid);
                barrier_lds();
            }
            // consumed-counter: fire-and-forget, one per block per iter
            if (tid == 0)
                __hip_atomic_fetch_add(cons0, 1u, __ATOMIC_RELAXED, __HIP_MEMORY_SCOPE_AGENT);
            if (!do1) continue;

            floatx4 acc[3][2];
#pragma unroll
            for (int g = 0; g < 3; g++) { acc[g][0] = (floatx4){0,0,0,0}; acc[g][1] = (floatx4){0,0,0,0}; }
            if (mat == 0)
                wave_gemm(shA_hi, shA_lo, WS + 2 * PLANE_U, WS + 3 * PLANE_U, jbg, lane, acc);
            else if (!l1z)
                wave_gemm(shB_hi, shB_lo, WS + 4 * PLANE_U, WS + 5 * PLANE_U, jbg, lane, acc);

            if (mat == 1) {
#pragma unroll
                for (int g = 0; g < 3; g++)
#pragma unroll
                    for (int m = 0; m < 2; m++)
#pragma unroll
                        for (int r = 0; r < 4; r++)
                            ldH[jbsub][g][m * 16 + quad * 4 + r][jlo] = acc[g][m][r];
            }
            barrier_lds();

            if (mat == 0) {
                ull_t* const dst = HQ + (size_t)(3 + ((k - 1) & 1)) * HP_E;
                const ull_t tag = ((ull_t)k) << 32;
#pragma unroll
                for (int m = 0; m < 2; m++) {
#pragma unroll
                    for (int r = 0; r < 4; r++) {
                        const int row = m * 16 + quad * 4 + r;
                        const float hp = l1z ? 0.f : lds_h(shB_hi, shB_lo, row * 264 + j);
                        const float ar  = acc[0][m][r] + ldH[jbsub][0][row][jlo] + b_r;
                        const float az  = acc[1][m][r] + ldH[jbsub][1][row][jlo] + b_z;
                        const float inn = acc[2][m][r] + b_in;
                        const float hn  = ldH[jbsub][2][row][jlo] + b_hn;
                        const float rg = fsig(ar), zg = fsig(az);
                        const float nn = ftanh(inn + rg * hn);
                        const float hv = zg * (hp - nn) + nn;
                        ast8(dst + (b0 + row) * 256 + j, (ull_t)packsplit(hv) | tag);
                    }
                }
            }
            barrier_lds();   // LDS reuse guard
        }
    }
}

__global__ __launch_bounds__(256) void classifier_kernel(
    const ushort_t* __restrict__ WS,
    const float* __restrict__ Wout, const float* __restrict__ bout,
    float* __restrict__ out)
{
    __shared__ float hs[32][C_H + 4];
    __shared__ float lg[32 * C_OUT];
    const int tid = threadIdx.x;
    const int b0  = blockIdx.x * 32;
    // final h1_{364}: plane 3 + (364 & 1) = 3; value = low 32 bits
    const ull_t* hp1 = (const ull_t*)(WS + US_H) + 3 * HP_E;
#pragma unroll
    for (int i = 0; i < 32; i++) {
        uint_t u = (uint_t)ald8(hp1 + (b0 + i) * 256 + tid);
        hs[i][tid] = __uint_as_float(u & 0xffff0000u) + __uint_as_float(u << 16);
    }
    __syncthreads();
    for (int u = tid; u < 32 * C_OUT; u += 256) {
        int bb = u / C_OUT, o = u - bb * C_OUT;
        const float* wr = Wout + o * C_H;
        float acc = bout[o];
#pragma unroll 4
        for (int k = 0; k < C_H; k += 4) {
            float4 wv = *(const float4*)(wr + k);
            float4 hv = *(const float4*)(&hs[bb][k]);
            acc += wv.x*hv.x + wv.y*hv.y + wv.z*hv.z + wv.w*hv.w;
        }
        lg[u] = acc;
    }
    __syncthreads();
    if (tid < 32) {
        float mx = -1e30f;
#pragma unroll
        for (int o = 0; o < C_OUT; o++) mx = fmaxf(mx, lg[tid * C_OUT + o]);
        float e[C_OUT];
        float s = 0.0f;
#pragma unroll
        for (int o = 0; o < C_OUT; o++) { e[o] = __expf(lg[tid * C_OUT + o] - mx); s += e[o]; }
        float inv = 1.0f / s;
#pragma unroll
        for (int o = 0; o < C_OUT; o++) out[(b0 + tid) * C_OUT + o] = e[o] * inv;
    }
}

extern "C" void kernel_launch(void* const* d_in, const int* in_sizes, int n_in,
                              void* d_out, int out_size, void* d_ws, size_t ws_size,
                              hipStream_t stream) {
    const float* x    = (const float*)d_in[0];
    // d_in[1] = times (unused), d_in[2] = interpolation_method (unused)
    const float* Wih0 = (const float*)d_in[3];
    const float* Whh0 = (const float*)d_in[4];
    const float* bih0 = (const float*)d_in[5];
    const float* bhh0 = (const float*)d_in[6];
    const float* Wih1 = (const float*)d_in[7];
    const float* Whh1 = (const float*)d_in[8];
    const float* bih1 = (const float*)d_in[9];
    const float* bhh1 = (const float*)d_in[10];
    const float* Wout = (const float*)d_in[11];
    const float* bout = (const float*)d_in[12];
    float* out = (float*)d_out;
    ushort_t* WS = (ushort_t*)d_ws;

    // pack weights + zero tag planes/counters (every launch, incl. graph replay)
    prep_pack<<<144, 256, 0, stream>>>(Whh0, Wih1, Whh1, WS);
    // whole recurrence in ONE dispatch; sync = tagged data itself
    gru_persistent<<<NB, 256, 0, stream>>>(x, Wih0, bih0, bhh0, bih1, bhh1, WS);
    classifier_kernel<<<C_B / 32, 256, 0, stream>>>(WS, Wout, bout, out);
}